// Round 11
// baseline (1015.989 us; speedup 1.0000x reference)
//
#include <hip/hip_runtime.h>
#include <hip/hip_bf16.h>
#include <cstdint>
#include <cstddef>

typedef __bf16 bf16_t;
typedef bf16_t bf16x8 __attribute__((ext_vector_type(8)));
typedef float  f32x4  __attribute__((ext_vector_type(4)));

__device__ __forceinline__ void gl_lds16(const void* g, void* l) {
  __builtin_amdgcn_global_load_lds(
      (const __attribute__((address_space(1))) void*)g,
      (__attribute__((address_space(3))) void*)l, 16, 0, 0);
}

#define BAR()  __builtin_amdgcn_s_barrier()

// ---------------------------------------------------------------------------
// prep kernel: fused pack_x0 + 6 weight transposes (fp32 -> bf16, KxN -> Npad x Kpad)
// ---------------------------------------------------------------------------
__device__ __forceinline__ void transpose_tile(
    const float* __restrict__ W, bf16_t* __restrict__ Wt,
    int K, int N, int Kpad, int Npad, int bx, int by, int t)
{
  __shared__ float tile[32][33];
  const int tx = t & 31, ty = t >> 5;
  const int k0 = bx * 32, n0 = by * 32;
#pragma unroll
  for (int i = 0; i < 4; ++i) {
    int k = k0 + ty + i * 8, n = n0 + tx;
    tile[ty + i * 8][tx] = (k < K && n < N) ? W[(size_t)k * N + n] : 0.f;
  }
  __syncthreads();
#pragma unroll
  for (int i = 0; i < 4; ++i) {
    int n = n0 + ty + i * 8, k = k0 + tx;
    if (n < Npad && k < Kpad)
      Wt[(size_t)n * Kpad + k] = (bf16_t)tile[tx][ty + i * 8];
  }
}

__global__ __launch_bounds__(256) void prep_kernel(
    const float* __restrict__ y, bf16_t* __restrict__ X0,
    const float* __restrict__ eW1, bf16_t* __restrict__ W1t,
    const float* __restrict__ eW2, bf16_t* __restrict__ W2t,
    const float* __restrict__ eW3, bf16_t* __restrict__ W3t,
    const float* __restrict__ dW1, bf16_t* __restrict__ V1t,
    const float* __restrict__ dW2, bf16_t* __restrict__ V2t,
    const float* __restrict__ dW3, bf16_t* __restrict__ V3t)
{
  const int b = blockIdx.x;
  const int t = threadIdx.x;
  if (b < 16000) {
    const int idx = b * 256 + t;
    const int r = idx / 320, c = (idx % 320) * 8;
    bf16x8 v;
    if (c < 2520) {
      const float4 f0 = *(const float4*)(y + (size_t)r * 2520 + c);
      const float4 f1 = *(const float4*)(y + (size_t)r * 2520 + c + 4);
      v[0] = (bf16_t)f0.x; v[1] = (bf16_t)f0.y; v[2] = (bf16_t)f0.z; v[3] = (bf16_t)f0.w;
      v[4] = (bf16_t)f1.x; v[5] = (bf16_t)f1.y; v[6] = (bf16_t)f1.z; v[7] = (bf16_t)f1.w;
    } else {
#pragma unroll
      for (int j = 0; j < 8; ++j) v[j] = (bf16_t)0.f;
    }
    *(bf16x8*)(X0 + (size_t)r * 2560 + c) = v;
    return;
  }
  int lb = b - 16000;
  if (lb < 2560)      { transpose_tile(eW1, W1t, 2520, 1024, 2560, 1024, lb % 80, lb / 80, t); return; }
  lb -= 2560;
  if (lb < 1024)      { transpose_tile(eW2, W2t, 1024, 1024, 1024, 1024, lb % 32, lb / 32, t); return; }
  lb -= 1024;
  if (lb < 2048)      { transpose_tile(eW3, W3t, 1024, 2048, 1024, 2048, lb % 32, lb / 32, t); return; }
  lb -= 2048;
  if (lb < 2048)      { transpose_tile(dW1, V1t, 2048, 1024, 2048, 1024, lb % 64, lb / 64, t); return; }
  lb -= 2048;
  if (lb < 1024)      { transpose_tile(dW2, V2t, 1024, 1024, 1024, 1024, lb % 32, lb / 32, t); return; }
  lb -= 1024;
  transpose_tile(dW3, V3t, 1024, 2520, 1024, 2560, lb % 32, lb / 32, t);
}

// ---------------------------------------------------------------------------
// 256x128 GEMM, BK=32. R11: B operand bypasses LDS -- loaded per-wave from
// global (L2-resident weights) straight into registers; next-tile B reloads
// in place after each bcur[nj]'s last MFMA (nj-outer order). LDS holds A only:
// 3 slots x 8KB = 24KB, depth-2 prefetch via gl_lds16. TWO blocks per CU.
// End-of-tile vmcnt(6) retires the 2 oldest VMEM ops = A(kt+1) stages
// (robust to any intra-tile issue order); B reg deps are compiler-guarded.
// 8 waves (4M x 2N), wave tile 64x64.
// Requires M%256==0, N%128==0, K%32==0, K/32 >= 2.
// ---------------------------------------------------------------------------
template<int ELU>
__global__ __launch_bounds__(512, 4) void gemm128(
    const bf16_t* __restrict__ A, const bf16_t* __restrict__ Bt,
    const float* __restrict__ bias,
    bf16_t* __restrict__ Cb, float* __restrict__ Cf,
    int M, int N, int K, int Nlog)
{
  __shared__ __align__(16) bf16_t lds[24576];   // 3 x 8192 elems (A 256x32)

  const int t  = threadIdx.x;
  const int w  = t >> 6, l = t & 63;
  const int fr = l & 15, kg = l >> 4;
  const int wm = (w >> 1) * 64, wn = (w & 1) * 64;   // 4M x 2N waves

  // bijective XCD-aware remap (m204)
  const int gx = gridDim.x;
  const int nwg = gx * (int)gridDim.y;
  int lin = blockIdx.y * gx + blockIdx.x;
  int q8 = nwg >> 3, r8 = nwg & 7, xcd = lin & 7, idx = lin >> 3;
  int swz = (xcd < r8 ? xcd * (q8 + 1) : r8 * (q8 + 1) + (xcd - r8) * q8) + idx;
  const int tn = (swz % gx) * 128;
  const int tm = (swz / gx) * 256;

  const int srow = t >> 2;
  const int scol = (t & 3) * 8;
  const int sdst = t * 8;

  const int NT = K >> 5;

  f32x4 acc[4][4];
#pragma unroll
  for (int i = 0; i < 4; ++i)
#pragma unroll
    for (int j = 0; j < 4; ++j) acc[i][j] = (f32x4){0.f, 0.f, 0.f, 0.f};

  auto stageA = [&](int slot, int kn) {
    bf16_t* d = lds + slot * 8192;
    gl_lds16(A + (size_t)(tm + srow) * K + kn + scol,       d + sdst);
    gl_lds16(A + (size_t)(tm + 128 + srow) * K + kn + scol, d + 4096 + sdst);
  };

  // per-lane B row pointers (advance by 32 elems after each load)
  const bf16_t* bp0 = Bt + (size_t)(tn + wn +  0 + fr) * K + kg * 8;
  const bf16_t* bp1 = Bt + (size_t)(tn + wn + 16 + fr) * K + kg * 8;
  const bf16_t* bp2 = Bt + (size_t)(tn + wn + 32 + fr) * K + kg * 8;
  const bf16_t* bp3 = Bt + (size_t)(tn + wn + 48 + fr) * K + kg * 8;

  bf16x8 bcur0, bcur1, bcur2, bcur3;

  // prologue: B(0) -> regs; stage A(0), A(1); full drain once.
  bcur0 = *(const bf16x8*)bp0; bp0 += 32;
  bcur1 = *(const bf16x8*)bp1; bp1 += 32;
  bcur2 = *(const bf16x8*)bp2; bp2 += 32;
  bcur3 = *(const bf16x8*)bp3; bp3 += 32;
  stageA(0, 0);
  stageA(1, 32);
  asm volatile("s_waitcnt vmcnt(0)" ::: "memory");
  BAR();

  for (int kt = 0; kt < NT; ++kt) {
    const int slot = kt % 3;
    const bf16_t* aH = lds + slot * 8192 + wm * 32;
    const bool pfB = (kt + 1 < NT);

    // stage A(kt+2) (slot (kt+2)%3: readers drained at tile kt-1's end)
    if (kt + 2 < NT) stageA((kt + 2) % 3, (kt + 2) << 5);

    bf16x8 af[4];
#pragma unroll
    for (int q = 0; q < 4; ++q)
      af[q] = *(const bf16x8*)(aH + (q * 16 + fr) * 32 + kg * 8);

    __builtin_amdgcn_s_setprio(1);
    // nj-outer: after bcur[nj]'s 4 MFMAs it is dead -> reload in place with
    // next tile's fragment (compiler guards the reg dependency).
#pragma unroll
    for (int mi = 0; mi < 4; ++mi)
      acc[mi][0] = __builtin_amdgcn_mfma_f32_16x16x32_bf16(af[mi], bcur0, acc[mi][0], 0, 0, 0);
    if (pfB) { bcur0 = *(const bf16x8*)bp0; bp0 += 32; }
#pragma unroll
    for (int mi = 0; mi < 4; ++mi)
      acc[mi][1] = __builtin_amdgcn_mfma_f32_16x16x32_bf16(af[mi], bcur1, acc[mi][1], 0, 0, 0);
    if (pfB) { bcur1 = *(const bf16x8*)bp1; bp1 += 32; }
#pragma unroll
    for (int mi = 0; mi < 4; ++mi)
      acc[mi][2] = __builtin_amdgcn_mfma_f32_16x16x32_bf16(af[mi], bcur2, acc[mi][2], 0, 0, 0);
    if (pfB) { bcur2 = *(const bf16x8*)bp2; bp2 += 32; }
#pragma unroll
    for (int mi = 0; mi < 4; ++mi)
      acc[mi][3] = __builtin_amdgcn_mfma_f32_16x16x32_bf16(af[mi], bcur3, acc[mi][3], 0, 0, 0);
    if (pfB) { bcur3 = *(const bf16x8*)bp3; bp3 += 32; }
    __builtin_amdgcn_s_setprio(0);

    // retire the 2 oldest VMEM ops = A(kt+1)'s stages -> resident before BAR
    asm volatile("s_waitcnt vmcnt(6)" ::: "memory");
    BAR();
  }

  // epilogue: C/D layout col = lane&15, row = (lane>>4)*4 + reg
#pragma unroll
  for (int mi = 0; mi < 4; ++mi) {
    const int row0 = tm + wm + mi * 16 + kg * 4;
#pragma unroll
    for (int nj = 0; nj < 4; ++nj) {
      const int col = tn + wn + nj * 16 + fr;
      const float bv = (col < Nlog) ? bias[col] : 0.f;
#pragma unroll
      for (int r = 0; r < 4; ++r) {
        float v = acc[mi][nj][r] + bv;
        if (ELU) v = (v > 0.f) ? v : expm1f(v);
        const int row = row0 + r;
        if (Cb) Cb[(size_t)row * N + col] = (bf16_t)v;
        if (Cf && col < Nlog) Cf[(size_t)row * Nlog + col] = v;
      }
    }
  }
}

// ---------------------------------------------------------------------------
// MFMA VQ: d = 0.5*||e||^2 - <z,e> via 16x16x32 bf16 MFMA (K padded with 0s).
// ---------------------------------------------------------------------------
__global__ __launch_bounds__(256) void vq_mfma(
    const float* __restrict__ ze, const float* __restrict__ emb,
    float* __restrict__ zq, bf16_t* __restrict__ zqb)
{
  __shared__ float  se[2048];
  __shared__ bf16_t seb[2048];
  const int t = threadIdx.x;
  for (int i = t; i < 2048; i += 256) { float v = emb[i]; se[i] = v; seb[i] = (bf16_t)v; }
  __syncthreads();

  const int l = t & 63, w = t >> 6;
  const int col = l & 15;
  const int ks8 = (l >> 4) * 8;
  const bool kact = (ks8 < 16);

  bf16x8 bfrag[8];
  float  hv[8];
#pragma unroll
  for (int cb = 0; cb < 8; ++cb) {
    float s = 0.f;
    bf16x8 bf;
#pragma unroll
    for (int j = 0; j < 8; ++j) bf[j] = (bf16_t)0.f;
    if (kact) {
      const float* ep = se + (cb * 16 + col) * 16 + ks8;
      float4 e0 = *(const float4*)ep;
      float4 e1 = *(const float4*)(ep + 4);
      bf[0] = (bf16_t)e0.x; bf[1] = (bf16_t)e0.y; bf[2] = (bf16_t)e0.z; bf[3] = (bf16_t)e0.w;
      bf[4] = (bf16_t)e1.x; bf[5] = (bf16_t)e1.y; bf[6] = (bf16_t)e1.z; bf[7] = (bf16_t)e1.w;
      s = e0.x*e0.x + e0.y*e0.y + e0.z*e0.z + e0.w*e0.w
        + e1.x*e1.x + e1.y*e1.y + e1.z*e1.z + e1.w*e1.w;
    }
    s += __shfl_xor(s, 16);
    s += __shfl_xor(s, 32);
    bfrag[cb] = bf;
    hv[cb] = 0.5f * s;
  }

  const int base_tile = blockIdx.x * 64 + w * 16;
  for (int it = 0; it < 16; ++it) {
    const int tile = base_tile + it;
    const int row = tile >> 3, g0 = (tile & 7) * 16;

    bf16x8 afrag;
#pragma unroll
    for (int j = 0; j < 8; ++j) afrag[j] = (bf16_t)0.f;
    if (kact) {
      const float* ap = ze + (size_t)row * 2048 + (g0 + col) * 16 + ks8;
      float4 a0 = *(const float4*)ap;
      float4 a1 = *(const float4*)(ap + 4);
      afrag[0] = (bf16_t)(-a0.x); afrag[1] = (bf16_t)(-a0.y);
      afrag[2] = (bf16_t)(-a0.z); afrag[3] = (bf16_t)(-a0.w);
      afrag[4] = (bf16_t)(-a1.x); afrag[5] = (bf16_t)(-a1.y);
      afrag[6] = (bf16_t)(-a1.z); afrag[7] = (bf16_t)(-a1.w);
    }

    f32x4 dd[8];
#pragma unroll
    for (int cb = 0; cb < 8; ++cb) {
      f32x4 c = (f32x4){hv[cb], hv[cb], hv[cb], hv[cb]};
      dd[cb] = __builtin_amdgcn_mfma_f32_16x16x32_bf16(afrag, bfrag[cb], c, 0, 0, 0);
    }

#pragma unroll
    for (int r = 0; r < 4; ++r) {
      float bd = dd[0][r]; int bi = col;
#pragma unroll
      for (int cb = 1; cb < 8; ++cb) {
        float v = dd[cb][r];
        int   ci = cb * 16 + col;
        if (v < bd) { bd = v; bi = ci; }
      }
#pragma unroll
      for (int m = 1; m < 16; m <<= 1) {
        float od = __shfl_xor(bd, m);
        int   oi = __shfl_xor(bi, m);
        if (od < bd || (od == bd && oi < bi)) { bd = od; bi = oi; }
      }
      if (col == r) {
        const int tok = (l >> 4) * 4 + r;
        const size_t go = ((size_t)row * 128 + g0 + tok) * 16;
        const float*  e  = se  + bi * 16;
        const bf16_t* eb = seb + bi * 16;
#pragma unroll
        for (int v = 0; v < 4; ++v)
          *(float4*)(zq + go + v * 4) = ((const float4*)e)[v];
        *(bf16x8*)(zqb + go)     = ((const bf16x8*)eb)[0];
        *(bf16x8*)(zqb + go + 8) = ((const bf16x8*)eb)[1];
      }
    }
  }
}

// ---------------------------------------------------------------------------
extern "C" void kernel_launch(void* const* d_in, const int* in_sizes, int n_in,
                              void* d_out, int out_size, void* d_ws, size_t ws_size,
                              hipStream_t stream)
{
  const float* y   = (const float*)d_in[0];
  const float* emb = (const float*)d_in[1];
  const float* eW1 = (const float*)d_in[2];
  const float* eb1 = (const float*)d_in[3];
  const float* eW2 = (const float*)d_in[4];
  const float* eb2 = (const float*)d_in[5];
  const float* eW3 = (const float*)d_in[6];
  const float* eb3 = (const float*)d_in[7];
  const float* dW1 = (const float*)d_in[8];
  const float* db1 = (const float*)d_in[9];
  const float* dW2 = (const float*)d_in[10];
  const float* db2 = (const float*)d_in[11];
  const float* dW3 = (const float*)d_in[12];
  const float* db3 = (const float*)d_in[13];

  float* out = (float*)d_out;               // [12800][2520]
  float* ze  = out + 32256000;              // [12800][2048]
  float* zq  = ze + 26214400;               // [12800][2048]

  uint8_t* ws = (uint8_t*)d_ws;
  size_t off = 0;
  auto alloc = [&](size_t bytes) -> void* {
    void* p = ws + off; off += (bytes + 255) & ~(size_t)255; return p;
  };
  bf16_t* X0  = (bf16_t*)alloc(12800ULL * 2560 * 2);
  bf16_t* W1t = (bf16_t*)alloc(1024ULL * 2560 * 2);
  bf16_t* W2t = (bf16_t*)alloc(1024ULL * 1024 * 2);
  bf16_t* W3t = (bf16_t*)alloc(2048ULL * 1024 * 2);
  bf16_t* V1t = (bf16_t*)alloc(1024ULL * 2048 * 2);
  bf16_t* V2t = (bf16_t*)alloc(1024ULL * 1024 * 2);
  bf16_t* V3t = (bf16_t*)alloc(2560ULL * 1024 * 2);
  bf16_t* H1  = (bf16_t*)alloc(12800ULL * 1024 * 2);
  bf16_t* H2  = (bf16_t*)alloc(12800ULL * 1024 * 2);
  bf16_t* ZQb = (bf16_t*)alloc(12800ULL * 2048 * 2);

  prep_kernel<<<27264, 256, 0, stream>>>(y, X0, eW1, W1t, eW2, W2t, eW3, W3t,
                                         dW1, V1t, dW2, V2t, dW3, V3t);

  // encoder
  gemm128<1><<<dim3(8, 50), 512, 0, stream>>>(X0, W1t, eb1, H1, nullptr, 12800, 1024, 2560, 1024);
  gemm128<1><<<dim3(8, 50), 512, 0, stream>>>(H1, W2t, eb2, H2, nullptr, 12800, 1024, 1024, 1024);
  gemm128<0><<<dim3(16, 50), 512, 0, stream>>>(H2, W3t, eb3, nullptr, ze, 12800, 2048, 1024, 2048);
  // vector quantize
  vq_mfma<<<1600, 256, 0, stream>>>(ze, emb, zq, ZQb);
  // decoder
  gemm128<1><<<dim3(8, 50), 512, 0, stream>>>(ZQb, V1t, db1, H1, nullptr, 12800, 1024, 2048, 1024);
  gemm128<1><<<dim3(8, 50), 512, 0, stream>>>(H1, V2t, db2, H2, nullptr, 12800, 1024, 1024, 1024);
  gemm128<0><<<dim3(20, 50), 512, 0, stream>>>(H2, V3t, db3, nullptr, out, 12800, 2560, 1024, 2520);
}

// Round 13
// 670.999 us; speedup vs baseline: 1.5141x; 1.5141x over previous
//
#include <hip/hip_runtime.h>
#include <hip/hip_bf16.h>
#include <cstdint>
#include <cstddef>

typedef __bf16 bf16_t;
typedef bf16_t bf16x8 __attribute__((ext_vector_type(8)));
typedef float  f32x4  __attribute__((ext_vector_type(4)));

__device__ __forceinline__ void gl_lds16(const void* g, void* l) {
  __builtin_amdgcn_global_load_lds(
      (const __attribute__((address_space(1))) void*)g,
      (__attribute__((address_space(3))) void*)l, 16, 0, 0);
}

#define BAR()  __builtin_amdgcn_s_barrier()

// ---------------------------------------------------------------------------
// prep kernel: fused pack_x0 + 6 weight transposes (fp32 -> bf16, KxN -> Npad x Kpad)
// ---------------------------------------------------------------------------
__device__ __forceinline__ void transpose_tile(
    const float* __restrict__ W, bf16_t* __restrict__ Wt,
    int K, int N, int Kpad, int Npad, int bx, int by, int t)
{
  __shared__ float tile[32][33];
  const int tx = t & 31, ty = t >> 5;
  const int k0 = bx * 32, n0 = by * 32;
#pragma unroll
  for (int i = 0; i < 4; ++i) {
    int k = k0 + ty + i * 8, n = n0 + tx;
    tile[ty + i * 8][tx] = (k < K && n < N) ? W[(size_t)k * N + n] : 0.f;
  }
  __syncthreads();
#pragma unroll
  for (int i = 0; i < 4; ++i) {
    int n = n0 + ty + i * 8, k = k0 + tx;
    if (n < Npad && k < Kpad)
      Wt[(size_t)n * Kpad + k] = (bf16_t)tile[tx][ty + i * 8];
  }
}

__global__ __launch_bounds__(256) void prep_kernel(
    const float* __restrict__ y, bf16_t* __restrict__ X0,
    const float* __restrict__ eW1, bf16_t* __restrict__ W1t,
    const float* __restrict__ eW2, bf16_t* __restrict__ W2t,
    const float* __restrict__ eW3, bf16_t* __restrict__ W3t,
    const float* __restrict__ dW1, bf16_t* __restrict__ V1t,
    const float* __restrict__ dW2, bf16_t* __restrict__ V2t,
    const float* __restrict__ dW3, bf16_t* __restrict__ V3t)
{
  const int b = blockIdx.x;
  const int t = threadIdx.x;
  if (b < 16000) {
    const int idx = b * 256 + t;
    const int r = idx / 320, c = (idx % 320) * 8;
    bf16x8 v;
    if (c < 2520) {
      const float4 f0 = *(const float4*)(y + (size_t)r * 2520 + c);
      const float4 f1 = *(const float4*)(y + (size_t)r * 2520 + c + 4);
      v[0] = (bf16_t)f0.x; v[1] = (bf16_t)f0.y; v[2] = (bf16_t)f0.z; v[3] = (bf16_t)f0.w;
      v[4] = (bf16_t)f1.x; v[5] = (bf16_t)f1.y; v[6] = (bf16_t)f1.z; v[7] = (bf16_t)f1.w;
    } else {
#pragma unroll
      for (int j = 0; j < 8; ++j) v[j] = (bf16_t)0.f;
    }
    *(bf16x8*)(X0 + (size_t)r * 2560 + c) = v;
    return;
  }
  int lb = b - 16000;
  if (lb < 2560)      { transpose_tile(eW1, W1t, 2520, 1024, 2560, 1024, lb % 80, lb / 80, t); return; }
  lb -= 2560;
  if (lb < 1024)      { transpose_tile(eW2, W2t, 1024, 1024, 1024, 1024, lb % 32, lb / 32, t); return; }
  lb -= 1024;
  if (lb < 2048)      { transpose_tile(eW3, W3t, 1024, 2048, 1024, 2048, lb % 32, lb / 32, t); return; }
  lb -= 2048;
  if (lb < 2048)      { transpose_tile(dW1, V1t, 2048, 1024, 2048, 1024, lb % 64, lb / 64, t); return; }
  lb -= 2048;
  if (lb < 1024)      { transpose_tile(dW2, V2t, 1024, 1024, 1024, 1024, lb % 32, lb / 32, t); return; }
  lb -= 1024;
  transpose_tile(dW3, V3t, 1024, 2520, 1024, 2560, lb % 32, lb / 32, t);
}

// ---------------------------------------------------------------------------
// 128x128 GEMM, BK=32, 3 LDS slots (48KB), depth-2 prefetch, THREE blocks/CU.
// R13 fix: EXACT tail waits. End-of-tile wait guarantees tile kt+1 resident:
//   kt+2 < NT  -> vmcnt(2)  (leave tile kt+2's 2 loads in flight)
//   kt+1 < NT  -> vmcnt(0)  (no newer stage; must drain tile kt+1's loads)
//   else       -> no wait (last tile)
// R12's vmcnt(2)-always was a race at tile NT-2 (no-op wait) -- latent in
// R9/R10 too, masked by longer tile bodies.
// 8 waves (4M x 2N), wave tile 32x64, acc[2][4].
// Requires M%128==0, N%128==0, K%32==0, K/32 >= 2.
// ---------------------------------------------------------------------------
template<int ELU>
__global__ __launch_bounds__(512, 6) void gemm128(
    const bf16_t* __restrict__ A, const bf16_t* __restrict__ Bt,
    const float* __restrict__ bias,
    bf16_t* __restrict__ Cb, float* __restrict__ Cf,
    int M, int N, int K, int Nlog)
{
  // slot = A 128x32 (8KB) + B 128x32 (8KB) = 16KB; 3 slots = 48KB
  __shared__ __align__(16) bf16_t lds[24576];

  const int t  = threadIdx.x;
  const int w  = t >> 6, l = t & 63;
  const int fr = l & 15, kg = l >> 4;
  const int wm = (w >> 1) * 32, wn = (w & 1) * 64;   // 4M x 2N waves, 32x64 each

  // bijective XCD-aware remap (m204)
  const int gx = gridDim.x;
  const int nwg = gx * (int)gridDim.y;
  int lin = blockIdx.y * gx + blockIdx.x;
  int q8 = nwg >> 3, r8 = nwg & 7, xcd = lin & 7, idx = lin >> 3;
  int swz = (xcd < r8 ? xcd * (q8 + 1) : r8 * (q8 + 1) + (xcd - r8) * q8) + idx;
  const int tn = (swz % gx) * 128;
  const int tm = (swz / gx) * 128;

  const int srow = t >> 2;          // 0..127
  const int scol = (t & 3) * 8;
  const int sdst = t * 8;

  const int NT = K >> 5;

  f32x4 acc[2][4];
#pragma unroll
  for (int i = 0; i < 2; ++i)
#pragma unroll
    for (int j = 0; j < 4; ++j) acc[i][j] = (f32x4){0.f, 0.f, 0.f, 0.f};

  auto stage = [&](int slot, int kn) {
    bf16_t* d = lds + slot * 8192;
    gl_lds16(A  + (size_t)(tm + srow) * K + kn + scol, d + sdst);
    gl_lds16(Bt + (size_t)(tn + srow) * K + kn + scol, d + 4096 + sdst);
  };

  // prologue: stage tiles 0,1; retire tile 0's 2 loads (leave tile 1's 2).
  stage(0, 0);
  stage(1, 32);
  asm volatile("s_waitcnt vmcnt(2)" ::: "memory");
  BAR();

  for (int kt = 0; kt < NT; ++kt) {
    const int slot = kt % 3;
    const bf16_t* aH = lds + slot * 8192 + wm * 32;           // wave's 32-row A view
    const bf16_t* bH = lds + slot * 8192 + 4096 + wn * 32;    // wave's 64-row B view

    // stage tile kt+2 (slot (kt+2)%3 = slot (kt-1)%3: readers drained)
    if (kt + 2 < NT) stage((kt + 2) % 3, (kt + 2) << 5);

    bf16x8 af[2], bf_[4];
#pragma unroll
    for (int q = 0; q < 2; ++q)
      af[q]  = *(const bf16x8*)(aH + (q * 16 + fr) * 32 + kg * 8);
#pragma unroll
    for (int q = 0; q < 4; ++q)
      bf_[q] = *(const bf16x8*)(bH + (q * 16 + fr) * 32 + kg * 8);
    __builtin_amdgcn_s_setprio(1);
#pragma unroll
    for (int mi = 0; mi < 2; ++mi)
#pragma unroll
      for (int nj = 0; nj < 4; ++nj)
        acc[mi][nj] = __builtin_amdgcn_mfma_f32_16x16x32_bf16(af[mi], bf_[nj], acc[mi][nj], 0, 0, 0);
    __builtin_amdgcn_s_setprio(0);

    // exact residency wait for tile kt+1 (see header)
    if (kt + 2 < NT) {
      asm volatile("s_waitcnt vmcnt(2)" ::: "memory");
    } else if (kt + 1 < NT) {
      asm volatile("s_waitcnt vmcnt(0)" ::: "memory");
    }
    BAR();
  }

  // epilogue: C/D layout col = lane&15, row = (lane>>4)*4 + reg
#pragma unroll
  for (int mi = 0; mi < 2; ++mi) {
    const int row0 = tm + wm + mi * 16 + kg * 4;
#pragma unroll
    for (int nj = 0; nj < 4; ++nj) {
      const int col = tn + wn + nj * 16 + fr;
      const float bv = (col < Nlog) ? bias[col] : 0.f;
#pragma unroll
      for (int r = 0; r < 4; ++r) {
        float v = acc[mi][nj][r] + bv;
        if (ELU) v = (v > 0.f) ? v : expm1f(v);
        const int row = row0 + r;
        if (Cb) Cb[(size_t)row * N + col] = (bf16_t)v;
        if (Cf && col < Nlog) Cf[(size_t)row * Nlog + col] = v;
      }
    }
  }
}

// ---------------------------------------------------------------------------
// MFMA VQ: d = 0.5*||e||^2 - <z,e> via 16x16x32 bf16 MFMA (K padded with 0s).
// ---------------------------------------------------------------------------
__global__ __launch_bounds__(256) void vq_mfma(
    const float* __restrict__ ze, const float* __restrict__ emb,
    float* __restrict__ zq, bf16_t* __restrict__ zqb)
{
  __shared__ float  se[2048];
  __shared__ bf16_t seb[2048];
  const int t = threadIdx.x;
  for (int i = t; i < 2048; i += 256) { float v = emb[i]; se[i] = v; seb[i] = (bf16_t)v; }
  __syncthreads();

  const int l = t & 63, w = t >> 6;
  const int col = l & 15;
  const int ks8 = (l >> 4) * 8;
  const bool kact = (ks8 < 16);

  bf16x8 bfrag[8];
  float  hv[8];
#pragma unroll
  for (int cb = 0; cb < 8; ++cb) {
    float s = 0.f;
    bf16x8 bf;
#pragma unroll
    for (int j = 0; j < 8; ++j) bf[j] = (bf16_t)0.f;
    if (kact) {
      const float* ep = se + (cb * 16 + col) * 16 + ks8;
      float4 e0 = *(const float4*)ep;
      float4 e1 = *(const float4*)(ep + 4);
      bf[0] = (bf16_t)e0.x; bf[1] = (bf16_t)e0.y; bf[2] = (bf16_t)e0.z; bf[3] = (bf16_t)e0.w;
      bf[4] = (bf16_t)e1.x; bf[5] = (bf16_t)e1.y; bf[6] = (bf16_t)e1.z; bf[7] = (bf16_t)e1.w;
      s = e0.x*e0.x + e0.y*e0.y + e0.z*e0.z + e0.w*e0.w
        + e1.x*e1.x + e1.y*e1.y + e1.z*e1.z + e1.w*e1.w;
    }
    s += __shfl_xor(s, 16);
    s += __shfl_xor(s, 32);
    bfrag[cb] = bf;
    hv[cb] = 0.5f * s;
  }

  const int base_tile = blockIdx.x * 64 + w * 16;
  for (int it = 0; it < 16; ++it) {
    const int tile = base_tile + it;
    const int row = tile >> 3, g0 = (tile & 7) * 16;

    bf16x8 afrag;
#pragma unroll
    for (int j = 0; j < 8; ++j) afrag[j] = (bf16_t)0.f;
    if (kact) {
      const float* ap = ze + (size_t)row * 2048 + (g0 + col) * 16 + ks8;
      float4 a0 = *(const float4*)ap;
      float4 a1 = *(const float4*)(ap + 4);
      afrag[0] = (bf16_t)(-a0.x); afrag[1] = (bf16_t)(-a0.y);
      afrag[2] = (bf16_t)(-a0.z); afrag[3] = (bf16_t)(-a0.w);
      afrag[4] = (bf16_t)(-a1.x); afrag[5] = (bf16_t)(-a1.y);
      afrag[6] = (bf16_t)(-a1.z); afrag[7] = (bf16_t)(-a1.w);
    }

    f32x4 dd[8];
#pragma unroll
    for (int cb = 0; cb < 8; ++cb) {
      f32x4 c = (f32x4){hv[cb], hv[cb], hv[cb], hv[cb]};
      dd[cb] = __builtin_amdgcn_mfma_f32_16x16x32_bf16(afrag, bfrag[cb], c, 0, 0, 0);
    }

#pragma unroll
    for (int r = 0; r < 4; ++r) {
      float bd = dd[0][r]; int bi = col;
#pragma unroll
      for (int cb = 1; cb < 8; ++cb) {
        float v = dd[cb][r];
        int   ci = cb * 16 + col;
        if (v < bd) { bd = v; bi = ci; }
      }
#pragma unroll
      for (int m = 1; m < 16; m <<= 1) {
        float od = __shfl_xor(bd, m);
        int   oi = __shfl_xor(bi, m);
        if (od < bd || (od == bd && oi < bi)) { bd = od; bi = oi; }
      }
      if (col == r) {
        const int tok = (l >> 4) * 4 + r;
        const size_t go = ((size_t)row * 128 + g0 + tok) * 16;
        const float*  e  = se  + bi * 16;
        const bf16_t* eb = seb + bi * 16;
#pragma unroll
        for (int v = 0; v < 4; ++v)
          *(float4*)(zq + go + v * 4) = ((const float4*)e)[v];
        *(bf16x8*)(zqb + go)     = ((const bf16x8*)eb)[0];
        *(bf16x8*)(zqb + go + 8) = ((const bf16x8*)eb)[1];
      }
    }
  }
}

// ---------------------------------------------------------------------------
extern "C" void kernel_launch(void* const* d_in, const int* in_sizes, int n_in,
                              void* d_out, int out_size, void* d_ws, size_t ws_size,
                              hipStream_t stream)
{
  const float* y   = (const float*)d_in[0];
  const float* emb = (const float*)d_in[1];
  const float* eW1 = (const float*)d_in[2];
  const float* eb1 = (const float*)d_in[3];
  const float* eW2 = (const float*)d_in[4];
  const float* eb2 = (const float*)d_in[5];
  const float* eW3 = (const float*)d_in[6];
  const float* eb3 = (const float*)d_in[7];
  const float* dW1 = (const float*)d_in[8];
  const float* db1 = (const float*)d_in[9];
  const float* dW2 = (const float*)d_in[10];
  const float* db2 = (const float*)d_in[11];
  const float* dW3 = (const float*)d_in[12];
  const float* db3 = (const float*)d_in[13];

  float* out = (float*)d_out;               // [12800][2520]
  float* ze  = out + 32256000;              // [12800][2048]
  float* zq  = ze + 26214400;               // [12800][2048]

  uint8_t* ws = (uint8_t*)d_ws;
  size_t off = 0;
  auto alloc = [&](size_t bytes) -> void* {
    void* p = ws + off; off += (bytes + 255) & ~(size_t)255; return p;
  };
  bf16_t* X0  = (bf16_t*)alloc(12800ULL * 2560 * 2);
  bf16_t* W1t = (bf16_t*)alloc(1024ULL * 2560 * 2);
  bf16_t* W2t = (bf16_t*)alloc(1024ULL * 1024 * 2);
  bf16_t* W3t = (bf16_t*)alloc(2048ULL * 1024 * 2);
  bf16_t* V1t = (bf16_t*)alloc(1024ULL * 2048 * 2);
  bf16_t* V2t = (bf16_t*)alloc(1024ULL * 1024 * 2);
  bf16_t* V3t = (bf16_t*)alloc(2560ULL * 1024 * 2);
  bf16_t* H1  = (bf16_t*)alloc(12800ULL * 1024 * 2);
  bf16_t* H2  = (bf16_t*)alloc(12800ULL * 1024 * 2);
  bf16_t* ZQb = (bf16_t*)alloc(12800ULL * 2048 * 2);

  prep_kernel<<<27264, 256, 0, stream>>>(y, X0, eW1, W1t, eW2, W2t, eW3, W3t,
                                         dW1, V1t, dW2, V2t, dW3, V3t);

  // encoder
  gemm128<1><<<dim3(8, 100), 512, 0, stream>>>(X0, W1t, eb1, H1, nullptr, 12800, 1024, 2560, 1024);
  gemm128<1><<<dim3(8, 100), 512, 0, stream>>>(H1, W2t, eb2, H2, nullptr, 12800, 1024, 1024, 1024);
  gemm128<0><<<dim3(16, 100), 512, 0, stream>>>(H2, W3t, eb3, nullptr, ze, 12800, 2048, 1024, 2048);
  // vector quantize
  vq_mfma<<<1600, 256, 0, stream>>>(ze, emb, zq, ZQb);
  // decoder
  gemm128<1><<<dim3(8, 100), 512, 0, stream>>>(ZQb, V1t, db1, H1, nullptr, 12800, 1024, 2048, 1024);
  gemm128<1><<<dim3(8, 100), 512, 0, stream>>>(H1, V2t, db2, H2, nullptr, 12800, 1024, 1024, 1024);
  gemm128<0><<<dim3(20, 100), 512, 0, stream>>>(H2, V3t, db3, nullptr, out, 12800, 2560, 1024, 2520);
}

// Round 14
// 611.952 us; speedup vs baseline: 1.6602x; 1.0965x over previous
//
#include <hip/hip_runtime.h>
#include <hip/hip_bf16.h>
#include <cstdint>
#include <cstddef>

typedef __bf16 bf16_t;
typedef bf16_t bf16x8 __attribute__((ext_vector_type(8)));
typedef float  f32x4  __attribute__((ext_vector_type(4)));

__device__ __forceinline__ void gl_lds16(const void* g, void* l) {
  __builtin_amdgcn_global_load_lds(
      (const __attribute__((address_space(1))) void*)g,
      (__attribute__((address_space(3))) void*)l, 16, 0, 0);
}

#define BAR()  __builtin_amdgcn_s_barrier()

// ---------------------------------------------------------------------------
// prep kernel: fused pack_x0 + 6 weight transposes (fp32 -> bf16, KxN -> Npad x Kpad)
// ---------------------------------------------------------------------------
__device__ __forceinline__ void transpose_tile(
    const float* __restrict__ W, bf16_t* __restrict__ Wt,
    int K, int N, int Kpad, int Npad, int bx, int by, int t)
{
  __shared__ float tile[32][33];
  const int tx = t & 31, ty = t >> 5;
  const int k0 = bx * 32, n0 = by * 32;
#pragma unroll
  for (int i = 0; i < 4; ++i) {
    int k = k0 + ty + i * 8, n = n0 + tx;
    tile[ty + i * 8][tx] = (k < K && n < N) ? W[(size_t)k * N + n] : 0.f;
  }
  __syncthreads();
#pragma unroll
  for (int i = 0; i < 4; ++i) {
    int n = n0 + ty + i * 8, k = k0 + tx;
    if (n < Npad && k < Kpad)
      Wt[(size_t)n * Kpad + k] = (bf16_t)tile[tx][ty + i * 8];
  }
}

__global__ __launch_bounds__(256) void prep_kernel(
    const float* __restrict__ y, bf16_t* __restrict__ X0,
    const float* __restrict__ eW1, bf16_t* __restrict__ W1t,
    const float* __restrict__ eW2, bf16_t* __restrict__ W2t,
    const float* __restrict__ eW3, bf16_t* __restrict__ W3t,
    const float* __restrict__ dW1, bf16_t* __restrict__ V1t,
    const float* __restrict__ dW2, bf16_t* __restrict__ V2t,
    const float* __restrict__ dW3, bf16_t* __restrict__ V3t)
{
  const int b = blockIdx.x;
  const int t = threadIdx.x;
  if (b < 16000) {
    const int idx = b * 256 + t;
    const int r = idx / 320, c = (idx % 320) * 8;
    bf16x8 v;
    if (c < 2520) {
      const float4 f0 = *(const float4*)(y + (size_t)r * 2520 + c);
      const float4 f1 = *(const float4*)(y + (size_t)r * 2520 + c + 4);
      v[0] = (bf16_t)f0.x; v[1] = (bf16_t)f0.y; v[2] = (bf16_t)f0.z; v[3] = (bf16_t)f0.w;
      v[4] = (bf16_t)f1.x; v[5] = (bf16_t)f1.y; v[6] = (bf16_t)f1.z; v[7] = (bf16_t)f1.w;
    } else {
#pragma unroll
      for (int j = 0; j < 8; ++j) v[j] = (bf16_t)0.f;
    }
    *(bf16x8*)(X0 + (size_t)r * 2560 + c) = v;
    return;
  }
  int lb = b - 16000;
  if (lb < 2560)      { transpose_tile(eW1, W1t, 2520, 1024, 2560, 1024, lb % 80, lb / 80, t); return; }
  lb -= 2560;
  if (lb < 1024)      { transpose_tile(eW2, W2t, 1024, 1024, 1024, 1024, lb % 32, lb / 32, t); return; }
  lb -= 1024;
  if (lb < 2048)      { transpose_tile(eW3, W3t, 1024, 2048, 1024, 2048, lb % 32, lb / 32, t); return; }
  lb -= 2048;
  if (lb < 2048)      { transpose_tile(dW1, V1t, 2048, 1024, 2048, 1024, lb % 64, lb / 64, t); return; }
  lb -= 2048;
  if (lb < 1024)      { transpose_tile(dW2, V2t, 1024, 1024, 1024, 1024, lb % 32, lb / 32, t); return; }
  lb -= 1024;
  transpose_tile(dW3, V3t, 1024, 2520, 1024, 2560, lb % 32, lb / 32, t);
}

// ---------------------------------------------------------------------------
// 256x128 GEMM, BK=32, 3 LDS slots (72KB), depth-2 prefetch, TWO blocks/CU
// (launch_bounds 512,4). 8 waves (4M x 2N), wave tile 64x64.
// R14 = R10 + EXACT tail waits (R12's lesson -- the latent race fix):
//   kt+2 < NT  -> vmcnt(3)  (leave tile kt+2's 3 loads in flight)
//   kt+1 < NT  -> vmcnt(0)  (no newer stage; drain tile kt+1's loads)
//   else       -> no wait (last tile)
// No explicit lgkmcnt (compiler emits fine-grained waits); interleaved
// A/B ds_reads so the first MFMA's operands land first.
// C[M][N] = A[M][K] @ Bt[N][K]^T + bias, optional ELU.
// Requires M%256==0, N%128==0, K%32==0, K/32 >= 2.
// ---------------------------------------------------------------------------
template<int ELU>
__global__ __launch_bounds__(512, 4) void gemm128(
    const bf16_t* __restrict__ A, const bf16_t* __restrict__ Bt,
    const float* __restrict__ bias,
    bf16_t* __restrict__ Cb, float* __restrict__ Cf,
    int M, int N, int K, int Nlog)
{
  // slot = A 256x32 (16KB) + B 128x32 (8KB) = 24KB; 3 slots = 72KB
  __shared__ __align__(16) bf16_t lds[36864];

  const int t  = threadIdx.x;
  const int w  = t >> 6, l = t & 63;
  const int fr = l & 15, kg = l >> 4;
  const int wm = (w >> 1) * 64, wn = (w & 1) * 64;   // 4M x 2N waves

  // bijective XCD-aware remap (m204)
  const int gx = gridDim.x;
  const int nwg = gx * (int)gridDim.y;
  int lin = blockIdx.y * gx + blockIdx.x;
  int q8 = nwg >> 3, r8 = nwg & 7, xcd = lin & 7, idx = lin >> 3;
  int swz = (xcd < r8 ? xcd * (q8 + 1) : r8 * (q8 + 1) + (xcd - r8) * q8) + idx;
  const int tn = (swz % gx) * 128;
  const int tm = (swz / gx) * 256;

  const int srow = t >> 2;
  const int scol = (t & 3) * 8;
  const int sdst = t * 8;

  const int NT = K >> 5;

  f32x4 acc[4][4];
#pragma unroll
  for (int i = 0; i < 4; ++i)
#pragma unroll
    for (int j = 0; j < 4; ++j) acc[i][j] = (f32x4){0.f, 0.f, 0.f, 0.f};

  auto stage = [&](int slot, int kn) {
    bf16_t* d = lds + slot * 12288;
    gl_lds16(A  + (size_t)(tm + srow) * K + kn + scol,       d + sdst);
    gl_lds16(A  + (size_t)(tm + 128 + srow) * K + kn + scol, d + 4096 + sdst);
    gl_lds16(Bt + (size_t)(tn + srow) * K + kn + scol,       d + 8192 + sdst);
  };

  // prologue: stage tiles 0,1; retire tile 0's 3 loads (leave tile 1's 3).
  stage(0, 0);
  stage(1, 32);
  asm volatile("s_waitcnt vmcnt(3)" ::: "memory");
  BAR();

  for (int kt = 0; kt < NT; ++kt) {
    const int slot = kt % 3;
    const bf16_t* aH = lds + slot * 12288 + wm * 32;          // wave's 64-row A view
    const bf16_t* bH = lds + slot * 12288 + 8192 + wn * 32;   // wave's 64-row B view

    // stage tile kt+2 (slot (kt+2)%3 = slot (kt-1)%3: readers drained)
    if (kt + 2 < NT) stage((kt + 2) % 3, (kt + 2) << 5);

    // interleaved reads: first MFMA's operands (af[0], bf_[0]) issue first;
    // no explicit lgkmcnt -- compiler inserts fine-grained waits per use.
    bf16x8 af[4], bf_[4];
#pragma unroll
    for (int q = 0; q < 4; ++q) {
      af[q]  = *(const bf16x8*)(aH + (q * 16 + fr) * 32 + kg * 8);
      bf_[q] = *(const bf16x8*)(bH + (q * 16 + fr) * 32 + kg * 8);
    }
    __builtin_amdgcn_s_setprio(1);
#pragma unroll
    for (int mi = 0; mi < 4; ++mi)
#pragma unroll
      for (int nj = 0; nj < 4; ++nj)
        acc[mi][nj] = __builtin_amdgcn_mfma_f32_16x16x32_bf16(af[mi], bf_[nj], acc[mi][nj], 0, 0, 0);
    __builtin_amdgcn_s_setprio(0);

    // exact residency wait for tile kt+1 (see header)
    if (kt + 2 < NT) {
      asm volatile("s_waitcnt vmcnt(3)" ::: "memory");
    } else if (kt + 1 < NT) {
      asm volatile("s_waitcnt vmcnt(0)" ::: "memory");
    }
    BAR();
  }

  // epilogue: C/D layout col = lane&15, row = (lane>>4)*4 + reg
#pragma unroll
  for (int mi = 0; mi < 4; ++mi) {
    const int row0 = tm + wm + mi * 16 + kg * 4;
#pragma unroll
    for (int nj = 0; nj < 4; ++nj) {
      const int col = tn + wn + nj * 16 + fr;
      const float bv = (col < Nlog) ? bias[col] : 0.f;
#pragma unroll
      for (int r = 0; r < 4; ++r) {
        float v = acc[mi][nj][r] + bv;
        if (ELU) v = (v > 0.f) ? v : expm1f(v);
        const int row = row0 + r;
        if (Cb) Cb[(size_t)row * N + col] = (bf16_t)v;
        if (Cf && col < Nlog) Cf[(size_t)row * Nlog + col] = v;
      }
    }
  }
}

// ---------------------------------------------------------------------------
// MFMA VQ: d = 0.5*||e||^2 - <z,e> via 16x16x32 bf16 MFMA (K padded with 0s).
// ---------------------------------------------------------------------------
__global__ __launch_bounds__(256) void vq_mfma(
    const float* __restrict__ ze, const float* __restrict__ emb,
    float* __restrict__ zq, bf16_t* __restrict__ zqb)
{
  __shared__ float  se[2048];
  __shared__ bf16_t seb[2048];
  const int t = threadIdx.x;
  for (int i = t; i < 2048; i += 256) { float v = emb[i]; se[i] = v; seb[i] = (bf16_t)v; }
  __syncthreads();

  const int l = t & 63, w = t >> 6;
  const int col = l & 15;
  const int ks8 = (l >> 4) * 8;
  const bool kact = (ks8 < 16);

  bf16x8 bfrag[8];
  float  hv[8];
#pragma unroll
  for (int cb = 0; cb < 8; ++cb) {
    float s = 0.f;
    bf16x8 bf;
#pragma unroll
    for (int j = 0; j < 8; ++j) bf[j] = (bf16_t)0.f;
    if (kact) {
      const float* ep = se + (cb * 16 + col) * 16 + ks8;
      float4 e0 = *(const float4*)ep;
      float4 e1 = *(const float4*)(ep + 4);
      bf[0] = (bf16_t)e0.x; bf[1] = (bf16_t)e0.y; bf[2] = (bf16_t)e0.z; bf[3] = (bf16_t)e0.w;
      bf[4] = (bf16_t)e1.x; bf[5] = (bf16_t)e1.y; bf[6] = (bf16_t)e1.z; bf[7] = (bf16_t)e1.w;
      s = e0.x*e0.x + e0.y*e0.y + e0.z*e0.z + e0.w*e0.w
        + e1.x*e1.x + e1.y*e1.y + e1.z*e1.z + e1.w*e1.w;
    }
    s += __shfl_xor(s, 16);
    s += __shfl_xor(s, 32);
    bfrag[cb] = bf;
    hv[cb] = 0.5f * s;
  }

  const int base_tile = blockIdx.x * 64 + w * 16;
  for (int it = 0; it < 16; ++it) {
    const int tile = base_tile + it;
    const int row = tile >> 3, g0 = (tile & 7) * 16;

    bf16x8 afrag;
#pragma unroll
    for (int j = 0; j < 8; ++j) afrag[j] = (bf16_t)0.f;
    if (kact) {
      const float* ap = ze + (size_t)row * 2048 + (g0 + col) * 16 + ks8;
      float4 a0 = *(const float4*)ap;
      float4 a1 = *(const float4*)(ap + 4);
      afrag[0] = (bf16_t)(-a0.x); afrag[1] = (bf16_t)(-a0.y);
      afrag[2] = (bf16_t)(-a0.z); afrag[3] = (bf16_t)(-a0.w);
      afrag[4] = (bf16_t)(-a1.x); afrag[5] = (bf16_t)(-a1.y);
      afrag[6] = (bf16_t)(-a1.z); afrag[7] = (bf16_t)(-a1.w);
    }

    f32x4 dd[8];
#pragma unroll
    for (int cb = 0; cb < 8; ++cb) {
      f32x4 c = (f32x4){hv[cb], hv[cb], hv[cb], hv[cb]};
      dd[cb] = __builtin_amdgcn_mfma_f32_16x16x32_bf16(afrag, bfrag[cb], c, 0, 0, 0);
    }

#pragma unroll
    for (int r = 0; r < 4; ++r) {
      float bd = dd[0][r]; int bi = col;
#pragma unroll
      for (int cb = 1; cb < 8; ++cb) {
        float v = dd[cb][r];
        int   ci = cb * 16 + col;
        if (v < bd) { bd = v; bi = ci; }
      }
#pragma unroll
      for (int m = 1; m < 16; m <<= 1) {
        float od = __shfl_xor(bd, m);
        int   oi = __shfl_xor(bi, m);
        if (od < bd || (od == bd && oi < bi)) { bd = od; bi = oi; }
      }
      if (col == r) {
        const int tok = (l >> 4) * 4 + r;
        const size_t go = ((size_t)row * 128 + g0 + tok) * 16;
        const float*  e  = se  + bi * 16;
        const bf16_t* eb = seb + bi * 16;
#pragma unroll
        for (int v = 0; v < 4; ++v)
          *(float4*)(zq + go + v * 4) = ((const float4*)e)[v];
        *(bf16x8*)(zqb + go)     = ((const bf16x8*)eb)[0];
        *(bf16x8*)(zqb + go + 8) = ((const bf16x8*)eb)[1];
      }
    }
  }
}

// ---------------------------------------------------------------------------
extern "C" void kernel_launch(void* const* d_in, const int* in_sizes, int n_in,
                              void* d_out, int out_size, void* d_ws, size_t ws_size,
                              hipStream_t stream)
{
  const float* y   = (const float*)d_in[0];
  const float* emb = (const float*)d_in[1];
  const float* eW1 = (const float*)d_in[2];
  const float* eb1 = (const float*)d_in[3];
  const float* eW2 = (const float*)d_in[4];
  const float* eb2 = (const float*)d_in[5];
  const float* eW3 = (const float*)d_in[6];
  const float* eb3 = (const float*)d_in[7];
  const float* dW1 = (const float*)d_in[8];
  const float* db1 = (const float*)d_in[9];
  const float* dW2 = (const float*)d_in[10];
  const float* db2 = (const float*)d_in[11];
  const float* dW3 = (const float*)d_in[12];
  const float* db3 = (const float*)d_in[13];

  float* out = (float*)d_out;               // [12800][2520]
  float* ze  = out + 32256000;              // [12800][2048]
  float* zq  = ze + 26214400;               // [12800][2048]

  uint8_t* ws = (uint8_t*)d_ws;
  size_t off = 0;
  auto alloc = [&](size_t bytes) -> void* {
    void* p = ws + off; off += (bytes + 255) & ~(size_t)255; return p;
  };
  bf16_t* X0  = (bf16_t*)alloc(12800ULL * 2560 * 2);
  bf16_t* W1t = (bf16_t*)alloc(1024ULL * 2560 * 2);
  bf16_t* W2t = (bf16_t*)alloc(1024ULL * 1024 * 2);
  bf16_t* W3t = (bf16_t*)alloc(2048ULL * 1024 * 2);
  bf16_t* V1t = (bf16_t*)alloc(1024ULL * 2048 * 2);
  bf16_t* V2t = (bf16_t*)alloc(1024ULL * 1024 * 2);
  bf16_t* V3t = (bf16_t*)alloc(2560ULL * 1024 * 2);
  bf16_t* H1  = (bf16_t*)alloc(12800ULL * 1024 * 2);
  bf16_t* H2  = (bf16_t*)alloc(12800ULL * 1024 * 2);
  bf16_t* ZQb = (bf16_t*)alloc(12800ULL * 2048 * 2);

  prep_kernel<<<27264, 256, 0, stream>>>(y, X0, eW1, W1t, eW2, W2t, eW3, W3t,
                                         dW1, V1t, dW2, V2t, dW3, V3t);

  // encoder
  gemm128<1><<<dim3(8, 50), 512, 0, stream>>>(X0, W1t, eb1, H1, nullptr, 12800, 1024, 2560, 1024);
  gemm128<1><<<dim3(8, 50), 512, 0, stream>>>(H1, W2t, eb2, H2, nullptr, 12800, 1024, 1024, 1024);
  gemm128<0><<<dim3(16, 50), 512, 0, stream>>>(H2, W3t, eb3, nullptr, ze, 12800, 2048, 1024, 2048);
  // vector quantize
  vq_mfma<<<1600, 256, 0, stream>>>(ze, emb, zq, ZQb);
  // decoder
  gemm128<1><<<dim3(8, 50), 512, 0, stream>>>(ZQb, V1t, db1, H1, nullptr, 12800, 1024, 2048, 1024);
  gemm128<1><<<dim3(8, 50), 512, 0, stream>>>(H1, V2t, db2, H2, nullptr, 12800, 1024, 1024, 1024);
  gemm128<0><<<dim3(20, 50), 512, 0, stream>>>(H2, V3t, db3, nullptr, out, 12800, 2560, 1024, 2520);
}